// Round 7
// baseline (197.572 us; speedup 1.0000x reference)
//
#include <hip/hip_runtime.h>
#include <hip/hip_bf16.h>

// Problem constants
#define BWIN 96      // b*gx*gy = 2*6*8
#define NTOK 320     // l*w1*w2 = 5*8*8
#define DIMX 256
#define HEADS 8
#define DH 32
#define INNER 256
#define CTXW 2560    // HEADS*NTOK
#define MPAD 328     // padded m-stride for P LDS strip (2-way banks on b128 reads)
#define ROWS_T 30720 // BWIN*NTOK

typedef __bf16 bf16x8 __attribute__((ext_vector_type(8)));
typedef __bf16 bf16x4 __attribute__((ext_vector_type(4)));
typedef float f32x4 __attribute__((ext_vector_type(4)));

// ---------------- Kernel 1: fused weight-cast + LayerNorm ----------------
__global__ __launch_bounds__(256) void k_pre(
    const float* __restrict__ wq, const float* __restrict__ wkv,
    const float* __restrict__ x, const float* __restrict__ g,
    const float* __restrict__ bt, __bf16* __restrict__ wT,
    __bf16* __restrict__ y)
{
    const int t = threadIdx.x;
    if (blockIdx.x < 768) {
        const int col = blockIdx.x;
        float v;
        if (col < 256)      v = wq[t * 256 + col];
        else if (col < 512) v = wkv[t * 512 + (col - 256)];
        else                v = wkv[t * 512 + 256 + (col - 512)];
        wT[(size_t)col * 256 + t] = (__bf16)v;
        return;
    }
    const int wave = t >> 6, lane = t & 63;
    const int row = (blockIdx.x - 768) * 4 + wave;
    const int bb = row / NTOK, n = row % NTOK;
    const int b_idx = bb / 48, x_idx = (bb % 48) >> 3, y_idx = bb & 7;
    const int l_idx = n >> 6, w1_idx = (n >> 3) & 7, w2_idx = n & 7;
    const size_t src =
        ((((((size_t)b_idx * 5 + l_idx) * 6 + x_idx) * 8 + y_idx) * 8 + w1_idx) * 8 + w2_idx) * (size_t)DIMX;

    const float4 xv = *(const float4*)(x + src + lane * 4);
    float s = xv.x + xv.y + xv.z + xv.w;
    float ss = xv.x * xv.x + xv.y * xv.y + xv.z * xv.z + xv.w * xv.w;
    #pragma unroll
    for (int o = 32; o > 0; o >>= 1) {
        s += __shfl_xor(s, o);
        ss += __shfl_xor(ss, o);
    }
    const float mu = s * (1.0f / DIMX);
    const float var = ss * (1.0f / DIMX) - mu * mu;
    const float rsig = rsqrtf(var + 1e-5f);
    const float4 g4 = *(const float4*)(g + lane * 4);
    const float4 b4 = *(const float4*)(bt + lane * 4);
    bf16x4 yo;
    yo[0] = (__bf16)((xv.x - mu) * rsig * g4.x + b4.x);
    yo[1] = (__bf16)((xv.y - mu) * rsig * g4.y + b4.y);
    yo[2] = (__bf16)((xv.z - mu) * rsig * g4.z + b4.z);
    yo[3] = (__bf16)((xv.w - mu) * rsig * g4.w + b4.w);
    *(bf16x4*)(y + (size_t)row * DIMX + lane * 4) = yo;
}

// ---------------- Kernel 2: QKV GEMM, 128x128 tile, LDS-staged ----------------
__global__ __launch_bounds__(256) void k_qkv(
    const __bf16* __restrict__ y, const __bf16* __restrict__ wT,
    __bf16* __restrict__ qb, __bf16* __restrict__ kb, __bf16* __restrict__ vb)
{
    __shared__ __bf16 yls[128][40];
    __shared__ __bf16 wls[128][40];
    const int t = threadIdx.x, wave = t >> 6, lane = t & 63;
    const int lr = lane & 15, lg = lane >> 4;
    const int wm = wave & 1, wn = wave >> 1;
    const int rbase = blockIdx.x * 128;
    const int cbase = blockIdx.y * 128;

    f32x4 acc[4][4];
    #pragma unroll
    for (int im = 0; im < 4; ++im)
        #pragma unroll
        for (int jn = 0; jn < 4; ++jn) acc[im][jn] = (f32x4){0.f, 0.f, 0.f, 0.f};

    const int srow = t >> 1, sseg = (t & 1) * 16;
    #pragma unroll
    for (int ks = 0; ks < 8; ++ks) {
        __syncthreads();
        #pragma unroll
        for (int j = 0; j < 2; ++j) {
            *(bf16x8*)&yls[srow][sseg + j * 8] =
                *(const bf16x8*)(y + (size_t)(rbase + srow) * DIMX + ks * 32 + sseg + j * 8);
            *(bf16x8*)&wls[srow][sseg + j * 8] =
                *(const bf16x8*)(wT + (size_t)(cbase + srow) * DIMX + ks * 32 + sseg + j * 8);
        }
        __syncthreads();

        bf16x8 yfr[4], wfr[4];
        #pragma unroll
        for (int jn = 0; jn < 4; ++jn) yfr[jn] = *(const bf16x8*)&yls[wm * 64 + jn * 16 + lr][lg * 8];
        #pragma unroll
        for (int im = 0; im < 4; ++im) wfr[im] = *(const bf16x8*)&wls[wn * 64 + im * 16 + lr][lg * 8];
        #pragma unroll
        for (int im = 0; im < 4; ++im)
            #pragma unroll
            for (int jn = 0; jn < 4; ++jn)
                acc[im][jn] = __builtin_amdgcn_mfma_f32_16x16x32_bf16(wfr[im], yfr[jn], acc[im][jn], 0, 0, 0);
    }

    #pragma unroll
    for (int im = 0; im < 4; ++im) {
        const int g = cbase + wn * 64 + im * 16 + lg * 4;
        __bf16* buf = (g < 256) ? qb : (g < 512) ? kb : vb;
        const int gc = g & 255;
        #pragma unroll
        for (int jn = 0; jn < 4; ++jn) {
            const int row = rbase + wm * 64 + jn * 16 + lr;
            bf16x4 p;
            #pragma unroll
            for (int i = 0; i < 4; ++i) p[i] = (__bf16)acc[im][jn][i];
            *(bf16x4*)(buf + (size_t)row * INNER + gc) = p;
        }
    }
}

// ---------------- Kernel 3: VW^T = (V_h @ wout_h)^T per (window, head) ----------------
__global__ __launch_bounds__(256) void k_vw(
    const __bf16* __restrict__ vb, const float* __restrict__ wout,
    __bf16* __restrict__ vwt)
{
    const int t = threadIdx.x, wave = t >> 6, lane = t & 63;
    const int lr = lane & 15, lg = lane >> 4;
    const int bb = blockIdx.x, h = blockIdx.y;
    const int m0 = wave * 80;

    bf16x8 afr[2];
    #pragma unroll
    for (int rt = 0; rt < 2; ++rt)
        #pragma unroll
        for (int j = 0; j < 8; ++j)
            afr[rt][j] = (__bf16)wout[(h * 32 + lg * 8 + j) * 32 + rt * 16 + lr];

    const __bf16* vbase = vb + ((size_t)bb * NTOK) * INNER + h * DH + lg * 8;
    __bf16* obase = vwt + ((size_t)(bb * HEADS + h) * DH) * NTOK;

    #pragma unroll
    for (int mt = 0; mt < 5; ++mt) {
        const int m = m0 + mt * 16 + lr;
        const bf16x8 bfr = *(const bf16x8*)(vbase + (size_t)m * INNER);
        #pragma unroll
        for (int rt = 0; rt < 2; ++rt) {
            const f32x4 d4 = __builtin_amdgcn_mfma_f32_16x16x32_bf16(
                afr[rt], bfr, (f32x4){0.f, 0.f, 0.f, 0.f}, 0, 0, 0);
            #pragma unroll
            for (int i = 0; i < 4; ++i) {
                const int drow = rt * 16 + lg * 4 + i;
                obase[(size_t)drow * NTOK + m0 + mt * 16 + lr] = (__bf16)d4[i];
            }
        }
    }
}

// ---------------- Kernel 4: per-head attention -> partial projected O ----------------
// grid (20, 96, 8): one 64-thr wave handles 16 q-rows x ONE head.
// S^T = mfma(K,Q): lane holds m = mt*16+lg*4+i, q = lr.
// P stored UNNORMALIZED (1/sum folded into epilogue scale).
__global__ __launch_bounds__(64) void k_attn(
    const __bf16* __restrict__ qb, const __bf16* __restrict__ kb,
    const __bf16* __restrict__ vwt, const float* __restrict__ ctx,
    float* __restrict__ part)
{
    __shared__ __bf16 plds[16][MPAD];   // [q-local][m]
    const int lane = threadIdx.x;
    const int lr = lane & 15, lg = lane >> 4;
    const int nw = blockIdx.x * 16;
    const int bb = blockIdx.y;
    const int h  = blockIdx.z;

    // Q as B-fragment
    const bf16x8 qfrag =
        *(const bf16x8*)(qb + ((size_t)(bb * NTOK + nw + lr)) * INNER + h * DH + lg * 8);

    // S^T tiles
    f32x4 s[20];
    const __bf16* kbase = kb + ((size_t)(bb * NTOK)) * INNER + h * DH + lg * 8;
    #pragma unroll
    for (int mt = 0; mt < 20; ++mt) {
        const bf16x8 kfrag = *(const bf16x8*)(kbase + (size_t)(mt * 16 + lr) * INNER);
        s[mt] = __builtin_amdgcn_mfma_f32_16x16x32_bf16(kfrag, qfrag,
                                                        (f32x4){0.f, 0.f, 0.f, 0.f}, 0, 0, 0);
    }

    // bias: lane's q-row, float4 per tile
    const float* ch = ctx + ((size_t)(bb * NTOK + nw + lr)) * CTXW + h * NTOK;
    #pragma unroll
    for (int mt = 0; mt < 20; ++mt) {
        const float4 c4 = *(const float4*)(ch + mt * 16 + lg * 4);
        s[mt][0] += c4.x; s[mt][1] += c4.y; s[mt][2] += c4.z; s[mt][3] += c4.w;
    }

    // softmax stats (max over local 80 + lanes {+16,+32})
    float mx = -3e38f;
    #pragma unroll
    for (int mt = 0; mt < 20; ++mt)
        #pragma unroll
        for (int i = 0; i < 4; ++i) mx = fmaxf(mx, s[mt][i]);
    mx = fmaxf(mx, __shfl_xor(mx, 16));
    mx = fmaxf(mx, __shfl_xor(mx, 32));

    // rolling exp -> bf16 -> LDS (unnormalized), accumulate sum
    float sum = 0.f;
    #pragma unroll
    for (int mt = 0; mt < 20; ++mt) {
        bf16x4 p4;
        #pragma unroll
        for (int i = 0; i < 4; ++i) {
            const float e = __expf(s[mt][i] - mx);
            sum += e;
            p4[i] = (__bf16)e;
        }
        *(bf16x4*)&plds[lr][mt * 16 + lg * 4] = p4;
    }
    sum += __shfl_xor(sum, 16);
    sum += __shfl_xor(sum, 32);
    const float rinv = 1.0f / sum;

    // O^T += VW^T x P^T
    f32x4 o0 = {0.f, 0.f, 0.f, 0.f}, o1 = {0.f, 0.f, 0.f, 0.f};
    const __bf16* vwb = vwt + ((size_t)(bb * HEADS + h) * DH) * NTOK;
    #pragma unroll
    for (int ks = 0; ks < 10; ++ks) {
        const bf16x8 pfrag = *(const bf16x8*)&plds[lr][ks * 32 + lg * 8];
        const bf16x8 vf0 = *(const bf16x8*)(vwb + (size_t)lr * NTOK + ks * 32 + lg * 8);
        const bf16x8 vf1 = *(const bf16x8*)(vwb + (size_t)(16 + lr) * NTOK + ks * 32 + lg * 8);
        o0 = __builtin_amdgcn_mfma_f32_16x16x32_bf16(vf0, pfrag, o0, 0, 0, 0);
        o1 = __builtin_amdgcn_mfma_f32_16x16x32_bf16(vf1, pfrag, o1, 0, 0, 0);
    }

    // partial store (normalize by rinv here)
    float* pdst = part + ((size_t)h * ROWS_T + (size_t)bb * NTOK + nw + lr) * DH + lg * 4;
    f32x4 r0, r1;
    #pragma unroll
    for (int i = 0; i < 4; ++i) { r0[i] = o0[i] * rinv; r1[i] = o1[i] * rinv; }
    *(f32x4*)(pdst)      = r0;
    *(f32x4*)(pdst + 16) = r1;
}

// ---------------- Kernel 5: head-reduce + output scatter ----------------
// grid (960), 256 thr: thread = one (row, 4-col group). out[row] = sum_h part[h][row].
__global__ __launch_bounds__(256) void k_red(
    const float* __restrict__ part, float* __restrict__ out)
{
    const int idx = blockIdx.x * 256 + threadIdx.x;   // ROWS_T*8 total
    const int row = idx >> 3, q4 = (idx & 7) * 4;
    f32x4 a = {0.f, 0.f, 0.f, 0.f};
    #pragma unroll
    for (int h = 0; h < HEADS; ++h) {
        const f32x4 p = *(const f32x4*)(part + ((size_t)h * ROWS_T + row) * DH + q4);
        #pragma unroll
        for (int i = 0; i < 4; ++i) a[i] += p[i];
    }
    const int bb = row / NTOK, n = row % NTOK;
    const int b_idx = bb / 48, x_idx = (bb % 48) >> 3, y_idx = bb & 7;
    const int l_idx = n >> 6, w1_idx = (n >> 3) & 7, w2_idx = n & 7;
    const size_t dst =
        ((((((size_t)b_idx * 5 + l_idx) * 6 + x_idx) * 8 + y_idx) * 8 + w1_idx) * 8 + w2_idx) * (size_t)DH;
    *(f32x4*)(out + dst + q4) = a;
}

extern "C" void kernel_launch(void* const* d_in, const int* in_sizes, int n_in,
                              void* d_out, int out_size, void* d_ws, size_t ws_size,
                              hipStream_t stream) {
    const float* x    = (const float*)d_in[0];
    const float* ctx  = (const float*)d_in[1];
    const float* wq   = (const float*)d_in[2];
    const float* wkv  = (const float*)d_in[3];
    const float* wout = (const float*)d_in[4];
    const float* ln_g = (const float*)d_in[5];
    const float* ln_b = (const float*)d_in[6];
    float* out = (float*)d_out;

    // workspace: qb|kb|vb|yb bf16 (SEG each), wT bf16, vwt bf16, part f32 (8*ROWS*32)
    const size_t SEG = (size_t)BWIN * NTOK * INNER;  // 7,864,320 elements
    __bf16* qb  = (__bf16*)d_ws;
    __bf16* kb  = qb + SEG;
    __bf16* vb  = kb + SEG;
    __bf16* yb  = vb + SEG;
    __bf16* wT  = yb + SEG;
    __bf16* vwt = wT + 768 * 256;
    float*  part = (float*)(vwt + SEG);

    const int ROWS = BWIN * NTOK;  // 30720
    k_pre<<<768 + ROWS / 4, 256, 0, stream>>>(wq, wkv, x, ln_g, ln_b, wT, yb);
    k_qkv<<<dim3(ROWS / 128, 6), 256, 0, stream>>>(yb, wT, qb, kb, vb);
    k_vw<<<dim3(BWIN, HEADS), 256, 0, stream>>>(vb, wout, vwt);
    k_attn<<<dim3(NTOK / 16, BWIN, HEADS), 64, 0, stream>>>(qb, kb, vwt, ctx, part);
    k_red<<<ROWS * 8 / 256, 256, 0, stream>>>(part, out);
}

// Round 8
// 181.342 us; speedup vs baseline: 1.0895x; 1.0895x over previous
//
#include <hip/hip_runtime.h>
#include <hip/hip_bf16.h>

// Problem constants
#define BWIN 96      // b*gx*gy = 2*6*8
#define NTOK 320     // l*w1*w2 = 5*8*8
#define DIMX 256
#define HEADS 8
#define DH 32
#define INNER 256
#define CTXW 2560    // HEADS*NTOK
#define MPAD 328     // padded m-stride for P LDS strip (2-way banks on b128 reads)
#define CPAD 324     // padded f32 row for ctx LDS tile (2-way banks on b128 reads)
#define ROWS_T 30720 // BWIN*NTOK

typedef __bf16 bf16x8 __attribute__((ext_vector_type(8)));
typedef __bf16 bf16x4 __attribute__((ext_vector_type(4)));
typedef float f32x4 __attribute__((ext_vector_type(4)));

// ---------------- Kernel 1: fused weight-cast + LayerNorm ----------------
__global__ __launch_bounds__(256) void k_pre(
    const float* __restrict__ wq, const float* __restrict__ wkv,
    const float* __restrict__ x, const float* __restrict__ g,
    const float* __restrict__ bt, __bf16* __restrict__ wT,
    __bf16* __restrict__ y)
{
    const int t = threadIdx.x;
    if (blockIdx.x < 768) {
        const int col = blockIdx.x;
        float v;
        if (col < 256)      v = wq[t * 256 + col];
        else if (col < 512) v = wkv[t * 512 + (col - 256)];
        else                v = wkv[t * 512 + 256 + (col - 512)];
        wT[(size_t)col * 256 + t] = (__bf16)v;
        return;
    }
    const int wave = t >> 6, lane = t & 63;
    const int row = (blockIdx.x - 768) * 4 + wave;
    const int bb = row / NTOK, n = row % NTOK;
    const int b_idx = bb / 48, x_idx = (bb % 48) >> 3, y_idx = bb & 7;
    const int l_idx = n >> 6, w1_idx = (n >> 3) & 7, w2_idx = n & 7;
    const size_t src =
        ((((((size_t)b_idx * 5 + l_idx) * 6 + x_idx) * 8 + y_idx) * 8 + w1_idx) * 8 + w2_idx) * (size_t)DIMX;

    const float4 xv = *(const float4*)(x + src + lane * 4);
    float s = xv.x + xv.y + xv.z + xv.w;
    float ss = xv.x * xv.x + xv.y * xv.y + xv.z * xv.z + xv.w * xv.w;
    #pragma unroll
    for (int o = 32; o > 0; o >>= 1) {
        s += __shfl_xor(s, o);
        ss += __shfl_xor(ss, o);
    }
    const float mu = s * (1.0f / DIMX);
    const float var = ss * (1.0f / DIMX) - mu * mu;
    const float rsig = rsqrtf(var + 1e-5f);
    const float4 g4 = *(const float4*)(g + lane * 4);
    const float4 b4 = *(const float4*)(bt + lane * 4);
    bf16x4 yo;
    yo[0] = (__bf16)((xv.x - mu) * rsig * g4.x + b4.x);
    yo[1] = (__bf16)((xv.y - mu) * rsig * g4.y + b4.y);
    yo[2] = (__bf16)((xv.z - mu) * rsig * g4.z + b4.z);
    yo[3] = (__bf16)((xv.w - mu) * rsig * g4.w + b4.w);
    *(bf16x4*)(y + (size_t)row * DIMX + lane * 4) = yo;
}

// ---------------- Kernel 2: QKV GEMM, 128x128 tile, LDS-staged ----------------
__global__ __launch_bounds__(256) void k_qkv(
    const __bf16* __restrict__ y, const __bf16* __restrict__ wT,
    __bf16* __restrict__ qb, __bf16* __restrict__ kb, __bf16* __restrict__ vb)
{
    __shared__ __bf16 yls[128][40];
    __shared__ __bf16 wls[128][40];
    const int t = threadIdx.x, wave = t >> 6, lane = t & 63;
    const int lr = lane & 15, lg = lane >> 4;
    const int wm = wave & 1, wn = wave >> 1;
    const int rbase = blockIdx.x * 128;
    const int cbase = blockIdx.y * 128;

    f32x4 acc[4][4];
    #pragma unroll
    for (int im = 0; im < 4; ++im)
        #pragma unroll
        for (int jn = 0; jn < 4; ++jn) acc[im][jn] = (f32x4){0.f, 0.f, 0.f, 0.f};

    const int srow = t >> 1, sseg = (t & 1) * 16;
    #pragma unroll
    for (int ks = 0; ks < 8; ++ks) {
        __syncthreads();
        #pragma unroll
        for (int j = 0; j < 2; ++j) {
            *(bf16x8*)&yls[srow][sseg + j * 8] =
                *(const bf16x8*)(y + (size_t)(rbase + srow) * DIMX + ks * 32 + sseg + j * 8);
            *(bf16x8*)&wls[srow][sseg + j * 8] =
                *(const bf16x8*)(wT + (size_t)(cbase + srow) * DIMX + ks * 32 + sseg + j * 8);
        }
        __syncthreads();

        bf16x8 yfr[4], wfr[4];
        #pragma unroll
        for (int jn = 0; jn < 4; ++jn) yfr[jn] = *(const bf16x8*)&yls[wm * 64 + jn * 16 + lr][lg * 8];
        #pragma unroll
        for (int im = 0; im < 4; ++im) wfr[im] = *(const bf16x8*)&wls[wn * 64 + im * 16 + lr][lg * 8];
        #pragma unroll
        for (int im = 0; im < 4; ++im)
            #pragma unroll
            for (int jn = 0; jn < 4; ++jn)
                acc[im][jn] = __builtin_amdgcn_mfma_f32_16x16x32_bf16(wfr[im], yfr[jn], acc[im][jn], 0, 0, 0);
    }

    #pragma unroll
    for (int im = 0; im < 4; ++im) {
        const int g = cbase + wn * 64 + im * 16 + lg * 4;
        __bf16* buf = (g < 256) ? qb : (g < 512) ? kb : vb;
        const int gc = g & 255;
        #pragma unroll
        for (int jn = 0; jn < 4; ++jn) {
            const int row = rbase + wm * 64 + jn * 16 + lr;
            bf16x4 p;
            #pragma unroll
            for (int i = 0; i < 4; ++i) p[i] = (__bf16)acc[im][jn][i];
            *(bf16x4*)(buf + (size_t)row * INNER + gc) = p;
        }
    }
}

// ---------------- Kernel 3: VW^T = (V_h @ wout_h)^T per (window, head) ----------------
__global__ __launch_bounds__(256) void k_vw(
    const __bf16* __restrict__ vb, const float* __restrict__ wout,
    __bf16* __restrict__ vwt)
{
    const int t = threadIdx.x, wave = t >> 6, lane = t & 63;
    const int lr = lane & 15, lg = lane >> 4;
    const int bb = blockIdx.x, h = blockIdx.y;
    const int m0 = wave * 80;

    bf16x8 afr[2];
    #pragma unroll
    for (int rt = 0; rt < 2; ++rt)
        #pragma unroll
        for (int j = 0; j < 8; ++j)
            afr[rt][j] = (__bf16)wout[(h * 32 + lg * 8 + j) * 32 + rt * 16 + lr];

    const __bf16* vbase = vb + ((size_t)bb * NTOK) * INNER + h * DH + lg * 8;
    __bf16* obase = vwt + ((size_t)(bb * HEADS + h) * DH) * NTOK;

    #pragma unroll
    for (int mt = 0; mt < 5; ++mt) {
        const int m = m0 + mt * 16 + lr;
        const bf16x8 bfr = *(const bf16x8*)(vbase + (size_t)m * INNER);
        #pragma unroll
        for (int rt = 0; rt < 2; ++rt) {
            const f32x4 d4 = __builtin_amdgcn_mfma_f32_16x16x32_bf16(
                afr[rt], bfr, (f32x4){0.f, 0.f, 0.f, 0.f}, 0, 0, 0);
            #pragma unroll
            for (int i = 0; i < 4; ++i) {
                const int drow = rt * 16 + lg * 4 + i;
                obase[(size_t)drow * NTOK + m0 + mt * 16 + lr] = (__bf16)d4[i];
            }
        }
    }
}

// ---------------- Kernel 4: per-head attention -> partial projected O ----------------
// grid (160, 96): h = x&7 (FASTEST -> h-siblings dispatch-adjacent, share DRAM rows),
// q-tile = x>>3. One 64-thr wave: 16 q-rows x one head.
// ctx staged via LDS with sequential flat reads; LDS region aliased for ctx (f32)
// then P (bf16) since ctx is dead after the bias add.
__global__ __launch_bounds__(64) void k_attn(
    const __bf16* __restrict__ qb, const __bf16* __restrict__ kb,
    const __bf16* __restrict__ vwt, const float* __restrict__ ctx,
    float* __restrict__ part)
{
    __shared__ char smem[16 * CPAD * 4];               // 20,736 B
    float (*ctxls)[CPAD] = (float(*)[CPAD])smem;       // [16][324] f32
    __bf16 (*plds)[MPAD] = (__bf16(*)[MPAD])smem;      // [16][328] bf16 (10.5 KB, aliased)

    const int lane = threadIdx.x;
    const int lr = lane & 15, lg = lane >> 4;
    const int h  = blockIdx.x & 7;
    const int nw = (blockIdx.x >> 3) * 16;
    const int bb = blockIdx.y;

    // --- stage ctx tile [16 rows][320 f32] with sequential bursts ---
    {
        const float* cbase = ctx + ((size_t)(bb * NTOK + nw)) * CTXW + h * NTOK;
        #pragma unroll
        for (int it = 0; it < 20; ++it) {
            const int f = it * 64 + lane;      // float4 index 0..1279
            const int r = f / 80, c = f % 80;  // 80 float4s per row
            const float4 v = *(const float4*)(cbase + (size_t)r * CTXW + c * 4);
            *(float4*)&ctxls[r][c * 4] = v;
        }
    }

    // Q as B-fragment
    const bf16x8 qfrag =
        *(const bf16x8*)(qb + ((size_t)(bb * NTOK + nw + lr)) * INNER + h * DH + lg * 8);

    // S^T tiles: A = K rows, B = Q
    f32x4 s[20];
    const __bf16* kbase = kb + ((size_t)(bb * NTOK)) * INNER + h * DH + lg * 8;
    #pragma unroll
    for (int mt = 0; mt < 20; ++mt) {
        const bf16x8 kfrag = *(const bf16x8*)(kbase + (size_t)(mt * 16 + lr) * INNER);
        s[mt] = __builtin_amdgcn_mfma_f32_16x16x32_bf16(kfrag, qfrag,
                                                        (f32x4){0.f, 0.f, 0.f, 0.f}, 0, 0, 0);
    }

    __syncthreads();   // ctx staging visible (single-wave: waitcnt + cheap barrier)

    // bias add from LDS (lane's q-row = lr, 4 consecutive m)
    #pragma unroll
    for (int mt = 0; mt < 20; ++mt) {
        const float4 c4 = *(const float4*)&ctxls[lr][mt * 16 + lg * 4];
        s[mt][0] += c4.x; s[mt][1] += c4.y; s[mt][2] += c4.z; s[mt][3] += c4.w;
    }

    // softmax stats
    float mx = -3e38f;
    #pragma unroll
    for (int mt = 0; mt < 20; ++mt)
        #pragma unroll
        for (int i = 0; i < 4; ++i) mx = fmaxf(mx, s[mt][i]);
    mx = fmaxf(mx, __shfl_xor(mx, 16));
    mx = fmaxf(mx, __shfl_xor(mx, 32));

    __syncthreads();   // all ctx reads done before P overwrites the region

    // rolling exp -> bf16 -> LDS (unnormalized), accumulate sum
    float sum = 0.f;
    #pragma unroll
    for (int mt = 0; mt < 20; ++mt) {
        bf16x4 p4;
        #pragma unroll
        for (int i = 0; i < 4; ++i) {
            const float e = __expf(s[mt][i] - mx);
            sum += e;
            p4[i] = (__bf16)e;
        }
        *(bf16x4*)&plds[lr][mt * 16 + lg * 4] = p4;
    }
    sum += __shfl_xor(sum, 16);
    sum += __shfl_xor(sum, 32);
    const float rinv = 1.0f / sum;

    __syncthreads();   // P writes visible to cross-lane fragment reads

    // O^T += VW^T x P^T
    f32x4 o0 = {0.f, 0.f, 0.f, 0.f}, o1 = {0.f, 0.f, 0.f, 0.f};
    const __bf16* vwb = vwt + ((size_t)(bb * HEADS + h) * DH) * NTOK;
    #pragma unroll
    for (int ks = 0; ks < 10; ++ks) {
        const bf16x8 pfrag = *(const bf16x8*)&plds[lr][ks * 32 + lg * 8];
        const bf16x8 vf0 = *(const bf16x8*)(vwb + (size_t)lr * NTOK + ks * 32 + lg * 8);
        const bf16x8 vf1 = *(const bf16x8*)(vwb + (size_t)(16 + lr) * NTOK + ks * 32 + lg * 8);
        o0 = __builtin_amdgcn_mfma_f32_16x16x32_bf16(vf0, pfrag, o0, 0, 0, 0);
        o1 = __builtin_amdgcn_mfma_f32_16x16x32_bf16(vf1, pfrag, o1, 0, 0, 0);
    }

    // partial store (normalize here)
    float* pdst = part + ((size_t)h * ROWS_T + (size_t)bb * NTOK + nw + lr) * DH + lg * 4;
    f32x4 r0, r1;
    #pragma unroll
    for (int i = 0; i < 4; ++i) { r0[i] = o0[i] * rinv; r1[i] = o1[i] * rinv; }
    *(f32x4*)(pdst)      = r0;
    *(f32x4*)(pdst + 16) = r1;
}

// ---------------- Kernel 5: head-reduce + output scatter ----------------
__global__ __launch_bounds__(256) void k_red(
    const float* __restrict__ part, float* __restrict__ out)
{
    const int idx = blockIdx.x * 256 + threadIdx.x;   // ROWS_T*8 total
    const int row = idx >> 3, q4 = (idx & 7) * 4;
    f32x4 a = {0.f, 0.f, 0.f, 0.f};
    #pragma unroll
    for (int h = 0; h < HEADS; ++h) {
        const f32x4 p = *(const f32x4*)(part + ((size_t)h * ROWS_T + row) * DH + q4);
        #pragma unroll
        for (int i = 0; i < 4; ++i) a[i] += p[i];
    }
    const int bb = row / NTOK, n = row % NTOK;
    const int b_idx = bb / 48, x_idx = (bb % 48) >> 3, y_idx = bb & 7;
    const int l_idx = n >> 6, w1_idx = (n >> 3) & 7, w2_idx = n & 7;
    const size_t dst =
        ((((((size_t)b_idx * 5 + l_idx) * 6 + x_idx) * 8 + y_idx) * 8 + w1_idx) * 8 + w2_idx) * (size_t)DH;
    *(f32x4*)(out + dst + q4) = a;
}

extern "C" void kernel_launch(void* const* d_in, const int* in_sizes, int n_in,
                              void* d_out, int out_size, void* d_ws, size_t ws_size,
                              hipStream_t stream) {
    const float* x    = (const float*)d_in[0];
    const float* ctx  = (const float*)d_in[1];
    const float* wq   = (const float*)d_in[2];
    const float* wkv  = (const float*)d_in[3];
    const float* wout = (const float*)d_in[4];
    const float* ln_g = (const float*)d_in[5];
    const float* ln_b = (const float*)d_in[6];
    float* out = (float*)d_out;

    // workspace: qb|kb|vb|yb bf16 (SEG each), wT bf16, vwt bf16, part f32
    const size_t SEG = (size_t)BWIN * NTOK * INNER;  // 7,864,320 elements
    __bf16* qb  = (__bf16*)d_ws;
    __bf16* kb  = qb + SEG;
    __bf16* vb  = kb + SEG;
    __bf16* yb  = vb + SEG;
    __bf16* wT  = yb + SEG;
    __bf16* vwt = wT + 768 * 256;
    float*  part = (float*)(vwt + SEG);

    const int ROWS = BWIN * NTOK;  // 30720
    k_pre<<<768 + ROWS / 4, 256, 0, stream>>>(wq, wkv, x, ln_g, ln_b, wT, yb);
    k_qkv<<<dim3(ROWS / 128, 6), 256, 0, stream>>>(yb, wT, qb, kb, vb);
    k_vw<<<dim3(BWIN, HEADS), 256, 0, stream>>>(vb, wout, vwt);
    k_attn<<<dim3(8 * (NTOK / 16), BWIN), 64, 0, stream>>>(qb, kb, vwt, ctx, part);
    k_red<<<ROWS * 8 / 256, 256, 0, stream>>>(part, out);
}

// Round 9
// 177.984 us; speedup vs baseline: 1.1101x; 1.0189x over previous
//
#include <hip/hip_runtime.h>
#include <hip/hip_bf16.h>

// Problem constants
#define BWIN 96      // b*gx*gy = 2*6*8
#define NTOK 320     // l*w1*w2 = 5*8*8
#define DIMX 256
#define HEADS 8
#define DH 32
#define INNER 256
#define CTXW 2560    // HEADS*NTOK
#define MPAD 328     // padded m-stride (bf16) for P/ctx LDS slices
#define ROWS_T 30720 // BWIN*NTOK

typedef __bf16 bf16x8 __attribute__((ext_vector_type(8)));
typedef __bf16 bf16x4 __attribute__((ext_vector_type(4)));
typedef float f32x4 __attribute__((ext_vector_type(4)));

// ---------------- Kernel 1: fused weight-cast + LayerNorm ----------------
__global__ __launch_bounds__(256) void k_pre(
    const float* __restrict__ wq, const float* __restrict__ wkv,
    const float* __restrict__ x, const float* __restrict__ g,
    const float* __restrict__ bt, __bf16* __restrict__ wT,
    __bf16* __restrict__ y)
{
    const int t = threadIdx.x;
    if (blockIdx.x < 768) {
        const int col = blockIdx.x;
        float v;
        if (col < 256)      v = wq[t * 256 + col];
        else if (col < 512) v = wkv[t * 512 + (col - 256)];
        else                v = wkv[t * 512 + 256 + (col - 512)];
        wT[(size_t)col * 256 + t] = (__bf16)v;
        return;
    }
    const int wave = t >> 6, lane = t & 63;
    const int row = (blockIdx.x - 768) * 4 + wave;
    const int bb = row / NTOK, n = row % NTOK;
    const int b_idx = bb / 48, x_idx = (bb % 48) >> 3, y_idx = bb & 7;
    const int l_idx = n >> 6, w1_idx = (n >> 3) & 7, w2_idx = n & 7;
    const size_t src =
        ((((((size_t)b_idx * 5 + l_idx) * 6 + x_idx) * 8 + y_idx) * 8 + w1_idx) * 8 + w2_idx) * (size_t)DIMX;

    const float4 xv = *(const float4*)(x + src + lane * 4);
    float s = xv.x + xv.y + xv.z + xv.w;
    float ss = xv.x * xv.x + xv.y * xv.y + xv.z * xv.z + xv.w * xv.w;
    #pragma unroll
    for (int o = 32; o > 0; o >>= 1) {
        s += __shfl_xor(s, o);
        ss += __shfl_xor(ss, o);
    }
    const float mu = s * (1.0f / DIMX);
    const float var = ss * (1.0f / DIMX) - mu * mu;
    const float rsig = rsqrtf(var + 1e-5f);
    const float4 g4 = *(const float4*)(g + lane * 4);
    const float4 b4 = *(const float4*)(bt + lane * 4);
    bf16x4 yo;
    yo[0] = (__bf16)((xv.x - mu) * rsig * g4.x + b4.x);
    yo[1] = (__bf16)((xv.y - mu) * rsig * g4.y + b4.y);
    yo[2] = (__bf16)((xv.z - mu) * rsig * g4.z + b4.z);
    yo[3] = (__bf16)((xv.w - mu) * rsig * g4.w + b4.w);
    *(bf16x4*)(y + (size_t)row * DIMX + lane * 4) = yo;
}

// ---------------- Kernel 2: QKV GEMM, 128x128 tile, LDS-staged ----------------
__global__ __launch_bounds__(256) void k_qkv(
    const __bf16* __restrict__ y, const __bf16* __restrict__ wT,
    __bf16* __restrict__ qb, __bf16* __restrict__ kb, __bf16* __restrict__ vb)
{
    __shared__ __bf16 yls[128][40];
    __shared__ __bf16 wls[128][40];
    const int t = threadIdx.x, wave = t >> 6, lane = t & 63;
    const int lr = lane & 15, lg = lane >> 4;
    const int wm = wave & 1, wn = wave >> 1;
    const int rbase = blockIdx.x * 128;
    const int cbase = blockIdx.y * 128;

    f32x4 acc[4][4];
    #pragma unroll
    for (int im = 0; im < 4; ++im)
        #pragma unroll
        for (int jn = 0; jn < 4; ++jn) acc[im][jn] = (f32x4){0.f, 0.f, 0.f, 0.f};

    const int srow = t >> 1, sseg = (t & 1) * 16;
    #pragma unroll
    for (int ks = 0; ks < 8; ++ks) {
        __syncthreads();
        #pragma unroll
        for (int j = 0; j < 2; ++j) {
            *(bf16x8*)&yls[srow][sseg + j * 8] =
                *(const bf16x8*)(y + (size_t)(rbase + srow) * DIMX + ks * 32 + sseg + j * 8);
            *(bf16x8*)&wls[srow][sseg + j * 8] =
                *(const bf16x8*)(wT + (size_t)(cbase + srow) * DIMX + ks * 32 + sseg + j * 8);
        }
        __syncthreads();

        bf16x8 yfr[4], wfr[4];
        #pragma unroll
        for (int jn = 0; jn < 4; ++jn) yfr[jn] = *(const bf16x8*)&yls[wm * 64 + jn * 16 + lr][lg * 8];
        #pragma unroll
        for (int im = 0; im < 4; ++im) wfr[im] = *(const bf16x8*)&wls[wn * 64 + im * 16 + lr][lg * 8];
        #pragma unroll
        for (int im = 0; im < 4; ++im)
            #pragma unroll
            for (int jn = 0; jn < 4; ++jn)
                acc[im][jn] = __builtin_amdgcn_mfma_f32_16x16x32_bf16(wfr[im], yfr[jn], acc[im][jn], 0, 0, 0);
    }

    #pragma unroll
    for (int im = 0; im < 4; ++im) {
        const int g = cbase + wn * 64 + im * 16 + lg * 4;
        __bf16* buf = (g < 256) ? qb : (g < 512) ? kb : vb;
        const int gc = g & 255;
        #pragma unroll
        for (int jn = 0; jn < 4; ++jn) {
            const int row = rbase + wm * 64 + jn * 16 + lr;
            bf16x4 p;
            #pragma unroll
            for (int i = 0; i < 4; ++i) p[i] = (__bf16)acc[im][jn][i];
            *(bf16x4*)(buf + (size_t)row * INNER + gc) = p;
        }
    }
}

// ---------------- Kernel 3: VW^T = (V_h @ wout_h)^T per (window, head) ----------------
__global__ __launch_bounds__(256) void k_vw(
    const __bf16* __restrict__ vb, const float* __restrict__ wout,
    __bf16* __restrict__ vwt)
{
    const int t = threadIdx.x, wave = t >> 6, lane = t & 63;
    const int lr = lane & 15, lg = lane >> 4;
    const int bb = blockIdx.x, h = blockIdx.y;
    const int m0 = wave * 80;

    bf16x8 afr[2];
    #pragma unroll
    for (int rt = 0; rt < 2; ++rt)
        #pragma unroll
        for (int j = 0; j < 8; ++j)
            afr[rt][j] = (__bf16)wout[(h * 32 + lg * 8 + j) * 32 + rt * 16 + lr];

    const __bf16* vbase = vb + ((size_t)bb * NTOK) * INNER + h * DH + lg * 8;
    __bf16* obase = vwt + ((size_t)(bb * HEADS + h) * DH) * NTOK;

    #pragma unroll
    for (int mt = 0; mt < 5; ++mt) {
        const int m = m0 + mt * 16 + lr;
        const bf16x8 bfr = *(const bf16x8*)(vbase + (size_t)m * INNER);
        #pragma unroll
        for (int rt = 0; rt < 2; ++rt) {
            const f32x4 d4 = __builtin_amdgcn_mfma_f32_16x16x32_bf16(
                afr[rt], bfr, (f32x4){0.f, 0.f, 0.f, 0.f}, 0, 0, 0);
            #pragma unroll
            for (int i = 0; i < 4; ++i) {
                const int drow = rt * 16 + lg * 4 + i;
                obase[(size_t)drow * NTOK + m0 + mt * 16 + lr] = (__bf16)d4[i];
            }
        }
    }
}

// ---------------- Kernel 4: attention, 4 heads/block (wide ctx bursts) ----------------
// grid (2*20, 96), 256 thr = 4 waves. hg = x&1 selects heads hg*4..hg*4+3;
// wave w handles head hg*4+w for the same 16-row q-tile. ctx staged as ONE
// 16-row x 5120B-contiguous panel (4 adjacent head slices), converted to bf16
// into per-head LDS slices. P aliases its head's slice (dead after bias add;
// within-wave lockstep -> no barrier). Single __syncthreads after stage.
__global__ __launch_bounds__(256) void k_attn(
    const __bf16* __restrict__ qb, const __bf16* __restrict__ kb,
    const __bf16* __restrict__ vwt, const float* __restrict__ ctx,
    float* __restrict__ part)
{
    __shared__ __bf16 ctxls[4][16][MPAD];   // 41,984 B; P aliases per-head slice
    const int t = threadIdx.x, wave = t >> 6, lane = t & 63;
    const int lr = lane & 15, lg = lane >> 4;
    const int hg = blockIdx.x & 1;
    const int nw = (blockIdx.x >> 1) * 16;
    const int bb = blockIdx.y;
    const int h  = hg * 4 + wave;

    // --- stage ctx panel: 16 rows x 1280 contiguous f32 -> bf16 slices ---
    {
        const float* cbase = ctx + ((size_t)(bb * NTOK + nw)) * CTXW + hg * 4 * NTOK;
        #pragma unroll
        for (int it = 0; it < 20; ++it) {
            const int f = it * 256 + t;          // float4 index, 0..5119
            const int r = f / 320, c4i = f % 320;
            const int hh = c4i / 80, cc = c4i % 80;
            const float4 v = *(const float4*)(cbase + (size_t)r * CTXW + c4i * 4);
            bf16x4 b;
            b[0] = (__bf16)v.x; b[1] = (__bf16)v.y; b[2] = (__bf16)v.z; b[3] = (__bf16)v.w;
            *(bf16x4*)&ctxls[hh][r][cc * 4] = b;
        }
    }

    // Q as B-fragment (issue before barrier to overlap stage latency)
    const bf16x8 qfrag =
        *(const bf16x8*)(qb + ((size_t)(bb * NTOK + nw + lr)) * INNER + h * DH + lg * 8);

    // S^T tiles: A = K rows, B = Q
    f32x4 s[20];
    const __bf16* kbase = kb + ((size_t)(bb * NTOK)) * INNER + h * DH + lg * 8;
    #pragma unroll
    for (int mt = 0; mt < 20; ++mt) {
        const bf16x8 kfrag = *(const bf16x8*)(kbase + (size_t)(mt * 16 + lr) * INNER);
        s[mt] = __builtin_amdgcn_mfma_f32_16x16x32_bf16(kfrag, qfrag,
                                                        (f32x4){0.f, 0.f, 0.f, 0.f}, 0, 0, 0);
    }

    __syncthreads();   // ctx staging visible to all waves

    // bias add from this wave's head slice (lane's q-row = lr, 4 consecutive m)
    #pragma unroll
    for (int mt = 0; mt < 20; ++mt) {
        const bf16x4 c4 = *(const bf16x4*)&ctxls[wave][lr][mt * 16 + lg * 4];
        #pragma unroll
        for (int i = 0; i < 4; ++i) s[mt][i] += (float)c4[i];
    }

    // softmax stats (max over local 80 + lanes {+16,+32})
    float mx = -3e38f;
    #pragma unroll
    for (int mt = 0; mt < 20; ++mt)
        #pragma unroll
        for (int i = 0; i < 4; ++i) mx = fmaxf(mx, s[mt][i]);
    mx = fmaxf(mx, __shfl_xor(mx, 16));
    mx = fmaxf(mx, __shfl_xor(mx, 32));

    // rolling exp -> bf16 -> P over the (dead) bias slice; accumulate sum.
    // Wave-lockstep: all lanes' bias reads precede these writes; no barrier needed.
    float sum = 0.f;
    #pragma unroll
    for (int mt = 0; mt < 20; ++mt) {
        bf16x4 p4;
        #pragma unroll
        for (int i = 0; i < 4; ++i) {
            const float e = __expf(s[mt][i] - mx);
            sum += e;
            p4[i] = (__bf16)e;
        }
        *(bf16x4*)&ctxls[wave][lr][mt * 16 + lg * 4] = p4;
    }
    sum += __shfl_xor(sum, 16);
    sum += __shfl_xor(sum, 32);
    const float rinv = 1.0f / sum;

    // O^T += VW^T x P^T
    f32x4 o0 = {0.f, 0.f, 0.f, 0.f}, o1 = {0.f, 0.f, 0.f, 0.f};
    const __bf16* vwb = vwt + ((size_t)(bb * HEADS + h) * DH) * NTOK;
    #pragma unroll
    for (int ks = 0; ks < 10; ++ks) {
        const bf16x8 pfrag = *(const bf16x8*)&ctxls[wave][lr][ks * 32 + lg * 8];
        const bf16x8 vf0 = *(const bf16x8*)(vwb + (size_t)lr * NTOK + ks * 32 + lg * 8);
        const bf16x8 vf1 = *(const bf16x8*)(vwb + (size_t)(16 + lr) * NTOK + ks * 32 + lg * 8);
        o0 = __builtin_amdgcn_mfma_f32_16x16x32_bf16(vf0, pfrag, o0, 0, 0, 0);
        o1 = __builtin_amdgcn_mfma_f32_16x16x32_bf16(vf1, pfrag, o1, 0, 0, 0);
    }

    // partial store: head-group partial (normalize here)
    float* pdst = part + ((size_t)hg * ROWS_T + (size_t)bb * NTOK + nw + lr) * DH + lg * 4;
    f32x4 r0, r1;
    #pragma unroll
    for (int i = 0; i < 4; ++i) { r0[i] = o0[i] * rinv; r1[i] = o1[i] * rinv; }
    // 4 waves of the block hit the same address set? No: different h -> same hg,
    // same (row, d) -> RACE unless waves accumulate. Use LDS cross-wave reduce:
    __shared__ float red[4][16][36];
    *(f32x4*)&red[wave][lr][lg * 4]      = r0;
    *(f32x4*)&red[wave][lr][16 + lg * 4] = r1;
    __syncthreads();
    // threads 0..511 would be needed for 16x32; with 256: each thread sums one (q,d)
    const int q = t >> 4, dd = (t & 15);      // q 0..15, two d-halves per thread
    #pragma unroll
    for (int half = 0; half < 2; ++half) {
        const int d = dd + half * 16;
        float a = red[0][q][ (d<16)? d : 16 + (d-16) ]  // red layout: [w][q][0..31]
                ;
        a = red[0][q][d] + red[1][q][d] + red[2][q][d] + red[3][q][d];
        part[((size_t)hg * ROWS_T + (size_t)bb * NTOK + nw + q) * DH + d] = a;
    }
}

// ---------------- Kernel 5: head-group reduce + output scatter ----------------
__global__ __launch_bounds__(256) void k_red(
    const float* __restrict__ part, float* __restrict__ out)
{
    const int idx = blockIdx.x * 256 + threadIdx.x;   // ROWS_T*8 total
    const int row = idx >> 3, q4 = (idx & 7) * 4;
    const f32x4 p0 = *(const f32x4*)(part + ((size_t)0 * ROWS_T + row) * DH + q4);
    const f32x4 p1 = *(const f32x4*)(part + ((size_t)1 * ROWS_T + row) * DH + q4);
    f32x4 a;
    #pragma unroll
    for (int i = 0; i < 4; ++i) a[i] = p0[i] + p1[i];
    const int bb = row / NTOK, n = row % NTOK;
    const int b_idx = bb / 48, x_idx = (bb % 48) >> 3, y_idx = bb & 7;
    const int l_idx = n >> 6, w1_idx = (n >> 3) & 7, w2_idx = n & 7;
    const size_t dst =
        ((((((size_t)b_idx * 5 + l_idx) * 6 + x_idx) * 8 + y_idx) * 8 + w1_idx) * 8 + w2_idx) * (size_t)DH;
    *(f32x4*)(out + dst + q4) = a;
}

extern "C" void kernel_launch(void* const* d_in, const int* in_sizes, int n_in,
                              void* d_out, int out_size, void* d_ws, size_t ws_size,
                              hipStream_t stream) {
    const float* x    = (const float*)d_in[0];
    const float* ctx  = (const float*)d_in[1];
    const float* wq   = (const float*)d_in[2];
    const float* wkv  = (const float*)d_in[3];
    const float* wout = (const float*)d_in[4];
    const float* ln_g = (const float*)d_in[5];
    const float* ln_b = (const float*)d_in[6];
    float* out = (float*)d_out;

    // workspace: qb|kb|vb|yb bf16 (SEG each), wT bf16, vwt bf16, part f32 (2*ROWS*32)
    const size_t SEG = (size_t)BWIN * NTOK * INNER;  // 7,864,320 elements
    __bf16* qb  = (__bf16*)d_ws;
    __bf16* kb  = qb + SEG;
    __bf16* vb  = kb + SEG;
    __bf16* yb  = vb + SEG;
    __bf16* wT  = yb + SEG;
    __bf16* vwt = wT + 768 * 256;
    float*  part = (float*)(vwt + SEG);

    const int ROWS = BWIN * NTOK;  // 30720
    k_pre<<<768 + ROWS / 4, 256, 0, stream>>>(wq, wkv, x, ln_g, ln_b, wT, yb);
    k_qkv<<<dim3(ROWS / 128, 6), 256, 0, stream>>>(yb, wT, qb, kb, vb);
    k_vw<<<dim3(BWIN, HEADS), 256, 0, stream>>>(vb, wout, vwt);
    k_attn<<<dim3(2 * (NTOK / 16), BWIN), 256, 0, stream>>>(qb, kb, vwt, ctx, part);
    k_red<<<ROWS * 8 / 256, 256, 0, stream>>>(part, out);
}

// Round 10
// 162.808 us; speedup vs baseline: 1.2135x; 1.0932x over previous
//
#include <hip/hip_runtime.h>
#include <hip/hip_bf16.h>

// Problem constants
#define BWIN 96      // b*gx*gy = 2*6*8
#define NTOK 320     // l*w1*w2 = 5*8*8
#define DIMX 256
#define HEADS 8
#define DH 32
#define INNER 256
#define CTXW 2560    // HEADS*NTOK
#define MPAD 328     // padded m-stride (bf16) for P/ctx/VW LDS rows
#define ROWS_T 30720 // BWIN*NTOK

typedef __bf16 bf16x8 __attribute__((ext_vector_type(8)));
typedef __bf16 bf16x4 __attribute__((ext_vector_type(4)));
typedef float f32x4 __attribute__((ext_vector_type(4)));

// ---------------- Kernel 1: fused weight-cast + LayerNorm ----------------
__global__ __launch_bounds__(256) void k_pre(
    const float* __restrict__ wq, const float* __restrict__ wkv,
    const float* __restrict__ x, const float* __restrict__ g,
    const float* __restrict__ bt, __bf16* __restrict__ wT,
    __bf16* __restrict__ y)
{
    const int t = threadIdx.x;
    if (blockIdx.x < 768) {
        const int col = blockIdx.x;
        float v;
        if (col < 256)      v = wq[t * 256 + col];
        else if (col < 512) v = wkv[t * 512 + (col - 256)];
        else                v = wkv[t * 512 + 256 + (col - 512)];
        wT[(size_t)col * 256 + t] = (__bf16)v;
        return;
    }
    const int wave = t >> 6, lane = t & 63;
    const int row = (blockIdx.x - 768) * 4 + wave;
    const int bb = row / NTOK, n = row % NTOK;
    const int b_idx = bb / 48, x_idx = (bb % 48) >> 3, y_idx = bb & 7;
    const int l_idx = n >> 6, w1_idx = (n >> 3) & 7, w2_idx = n & 7;
    const size_t src =
        ((((((size_t)b_idx * 5 + l_idx) * 6 + x_idx) * 8 + y_idx) * 8 + w1_idx) * 8 + w2_idx) * (size_t)DIMX;

    const float4 xv = *(const float4*)(x + src + lane * 4);
    float s = xv.x + xv.y + xv.z + xv.w;
    float ss = xv.x * xv.x + xv.y * xv.y + xv.z * xv.z + xv.w * xv.w;
    #pragma unroll
    for (int o = 32; o > 0; o >>= 1) {
        s += __shfl_xor(s, o);
        ss += __shfl_xor(ss, o);
    }
    const float mu = s * (1.0f / DIMX);
    const float var = ss * (1.0f / DIMX) - mu * mu;
    const float rsig = rsqrtf(var + 1e-5f);
    const float4 g4 = *(const float4*)(g + lane * 4);
    const float4 b4 = *(const float4*)(bt + lane * 4);
    bf16x4 yo;
    yo[0] = (__bf16)((xv.x - mu) * rsig * g4.x + b4.x);
    yo[1] = (__bf16)((xv.y - mu) * rsig * g4.y + b4.y);
    yo[2] = (__bf16)((xv.z - mu) * rsig * g4.z + b4.z);
    yo[3] = (__bf16)((xv.w - mu) * rsig * g4.w + b4.w);
    *(bf16x4*)(y + (size_t)row * DIMX + lane * 4) = yo;
}

// ---------------- Kernel 2: QKV GEMM -> head-major outputs ----------------
// grid (240, 6). Output layout: q/k/v[(bb*8+h)*320 + n][32] bf16 (head-major),
// so attention-side reads are fully sequential per (window, head).
__global__ __launch_bounds__(256) void k_qkv(
    const __bf16* __restrict__ y, const __bf16* __restrict__ wT,
    __bf16* __restrict__ qhb, __bf16* __restrict__ khb, __bf16* __restrict__ vhb)
{
    __shared__ __bf16 yls[128][40];
    __shared__ __bf16 wls[128][40];
    const int t = threadIdx.x, wave = t >> 6, lane = t & 63;
    const int lr = lane & 15, lg = lane >> 4;
    const int wm = wave & 1, wn = wave >> 1;
    const int rbase = blockIdx.x * 128;
    const int cbase = blockIdx.y * 128;

    f32x4 acc[4][4];
    #pragma unroll
    for (int im = 0; im < 4; ++im)
        #pragma unroll
        for (int jn = 0; jn < 4; ++jn) acc[im][jn] = (f32x4){0.f, 0.f, 0.f, 0.f};

    const int srow = t >> 1, sseg = (t & 1) * 16;
    #pragma unroll
    for (int ks = 0; ks < 8; ++ks) {
        __syncthreads();
        #pragma unroll
        for (int j = 0; j < 2; ++j) {
            *(bf16x8*)&yls[srow][sseg + j * 8] =
                *(const bf16x8*)(y + (size_t)(rbase + srow) * DIMX + ks * 32 + sseg + j * 8);
            *(bf16x8*)&wls[srow][sseg + j * 8] =
                *(const bf16x8*)(wT + (size_t)(cbase + srow) * DIMX + ks * 32 + sseg + j * 8);
        }
        __syncthreads();

        bf16x8 yfr[4], wfr[4];
        #pragma unroll
        for (int jn = 0; jn < 4; ++jn) yfr[jn] = *(const bf16x8*)&yls[wm * 64 + jn * 16 + lr][lg * 8];
        #pragma unroll
        for (int im = 0; im < 4; ++im) wfr[im] = *(const bf16x8*)&wls[wn * 64 + im * 16 + lr][lg * 8];
        #pragma unroll
        for (int im = 0; im < 4; ++im)
            #pragma unroll
            for (int jn = 0; jn < 4; ++jn)
                acc[im][jn] = __builtin_amdgcn_mfma_f32_16x16x32_bf16(wfr[im], yfr[jn], acc[im][jn], 0, 0, 0);
    }

    #pragma unroll
    for (int im = 0; im < 4; ++im) {
        const int g = cbase + wn * 64 + im * 16 + lg * 4;   // global col 0..767
        const int which = g >> 8;
        __bf16* buf = (which == 0) ? qhb : (which == 1) ? khb : vhb;
        const int hh = (g & 255) >> 5, d = g & 31;
        #pragma unroll
        for (int jn = 0; jn < 4; ++jn) {
            const int row = rbase + wm * 64 + jn * 16 + lr;
            const int bb2 = row / NTOK, n2 = row % NTOK;
            bf16x4 p;
            #pragma unroll
            for (int i = 0; i < 4; ++i) p[i] = (__bf16)acc[im][jn][i];
            *(bf16x4*)(buf + ((size_t)(bb2 * 8 + hh) * NTOK + n2) * DH + d) = p;
        }
    }
}

// ---------------- Kernel 3: VW^T = (V_h @ wout_h)^T per (window, head) ----------------
// vhb is head-major: V_h rows are 64B-contiguous. Output vwt[(bb*8+h)*32+d][m].
__global__ __launch_bounds__(256) void k_vw(
    const __bf16* __restrict__ vhb, const float* __restrict__ wout,
    __bf16* __restrict__ vwt)
{
    const int t = threadIdx.x, wave = t >> 6, lane = t & 63;
    const int lr = lane & 15, lg = lane >> 4;
    const int bb = blockIdx.x, h = blockIdx.y;
    const int m0 = wave * 80;

    bf16x8 afr[2];
    #pragma unroll
    for (int rt = 0; rt < 2; ++rt)
        #pragma unroll
        for (int j = 0; j < 8; ++j)
            afr[rt][j] = (__bf16)wout[(h * 32 + lg * 8 + j) * 32 + rt * 16 + lr];

    const __bf16* vbase = vhb + (size_t)(bb * 8 + h) * NTOK * DH + lg * 8;
    __bf16* obase = vwt + ((size_t)(bb * HEADS + h) * DH) * NTOK;

    #pragma unroll
    for (int mt = 0; mt < 5; ++mt) {
        const int m = m0 + mt * 16 + lr;
        const bf16x8 bfr = *(const bf16x8*)(vbase + (size_t)m * DH);
        #pragma unroll
        for (int rt = 0; rt < 2; ++rt) {
            const f32x4 d4 = __builtin_amdgcn_mfma_f32_16x16x32_bf16(
                afr[rt], bfr, (f32x4){0.f, 0.f, 0.f, 0.f}, 0, 0, 0);
            #pragma unroll
            for (int i = 0; i < 4; ++i) {
                const int drow = rt * 16 + lg * 4 + i;
                obase[(size_t)drow * NTOK + m0 + mt * 16 + lr] = (__bf16)d4[i];
            }
        }
    }
}

// ---------------- Kernel 4: K/VW-stationary attention ----------------
// grid (768) = (bb, h) with h fastest; 128 thr = 2 waves.
// Stage K (20KB) + VW^T (21KB) in LDS once; each wave loops 10 q-tiles with a
// reg-prefetched ctx pipeline. P aliases the (dead) ctx slice. No in-loop barriers.
__global__ __launch_bounds__(128) void k_attn(
    const __bf16* __restrict__ qhb, const __bf16* __restrict__ khb,
    const __bf16* __restrict__ vwt, const float* __restrict__ ctx,
    float* __restrict__ part)
{
    __shared__ __bf16 kls[NTOK][DH];        // 20,480 B  (b128 reads conflict-free)
    __shared__ __bf16 vwls[DH][MPAD];       // 20,992 B
    __shared__ __bf16 ctxls[2][16][MPAD];   // 20,992 B  (per-wave; P aliases)
    const int t = threadIdx.x, wave = t >> 6, lane = t & 63;
    const int lr = lane & 15, lg = lane >> 4;
    const int h = blockIdx.x & 7, bb = blockIdx.x >> 3;
    const size_t panel = (size_t)(bb * 8 + h);

    // --- stage K (fully sequential) ---
    const __bf16* kpan = khb + panel * NTOK * DH;
    #pragma unroll
    for (int i = 0; i < 10; ++i) {
        const int idx = i * 128 + t;          // 16B chunk id, 0..1279
        *(bf16x8*)&kls[idx >> 2][(idx & 3) * 8] = *(const bf16x8*)(kpan + idx * 8);
    }
    // --- stage VW^T (sequential) ---
    const __bf16* vpan = vwt + panel * DH * NTOK;
    #pragma unroll
    for (int i = 0; i < 10; ++i) {
        const int idx = i * 128 + t;
        const int r = idx / 40, c = (idx % 40) * 8;
        *(bf16x8*)&vwls[r][c] = *(const bf16x8*)(vpan + r * NTOK + c);
    }
    __syncthreads();

    const float* cpan = ctx + (size_t)bb * NTOK * CTXW + h * NTOK;
    const __bf16* qpan = qhb + panel * NTOK * DH;
    float* ppan = part + ((size_t)h * ROWS_T + (size_t)bb * NTOK) * DH;

    // prologue: prefetch ctx tile for iteration 0 (wave's q-tile = 2*it + wave)
    float4 creg[20];
    {
        const float* cb = cpan + (size_t)(wave * 16) * CTXW;
        #pragma unroll
        for (int j = 0; j < 20; ++j) {
            const int f = j * 64 + lane, r = f / 80, c = f % 80;
            creg[j] = *(const float4*)(cb + (size_t)r * CTXW + c * 4);
        }
    }

    for (int it = 0; it < 10; ++it) {
        const int nw = (it * 2 + wave) * 16;

        // write current ctx regs -> LDS (bf16)
        #pragma unroll
        for (int j = 0; j < 20; ++j) {
            const int f = j * 64 + lane, r = f / 80, c = f % 80;
            bf16x4 b;
            b[0] = (__bf16)creg[j].x; b[1] = (__bf16)creg[j].y;
            b[2] = (__bf16)creg[j].z; b[3] = (__bf16)creg[j].w;
            *(bf16x4*)&ctxls[wave][r][c * 4] = b;
        }
        // prefetch next tile (overlaps with the whole iteration below)
        if (it < 9) {
            const float* cb = cpan + (size_t)((it * 2 + 2 + wave) * 16) * CTXW;
            #pragma unroll
            for (int j = 0; j < 20; ++j) {
                const int f = j * 64 + lane, r = f / 80, c = f % 80;
                creg[j] = *(const float4*)(cb + (size_t)r * CTXW + c * 4);
            }
        }

        // Q fragment (head-major, 64B-strided)
        const bf16x8 qfrag = *(const bf16x8*)(qpan + (size_t)(nw + lr) * DH + lg * 8);

        // S^T = mfma(K, Q) from LDS
        f32x4 s[20];
        #pragma unroll
        for (int mt = 0; mt < 20; ++mt) {
            const bf16x8 kfrag = *(const bf16x8*)&kls[mt * 16 + lr][lg * 8];
            s[mt] = __builtin_amdgcn_mfma_f32_16x16x32_bf16(kfrag, qfrag,
                                                            (f32x4){0.f, 0.f, 0.f, 0.f}, 0, 0, 0);
        }

        // bias add from this wave's ctx slice
        #pragma unroll
        for (int mt = 0; mt < 20; ++mt) {
            const bf16x4 c4 = *(const bf16x4*)&ctxls[wave][lr][mt * 16 + lg * 4];
            #pragma unroll
            for (int i = 0; i < 4; ++i) s[mt][i] += (float)c4[i];
        }

        // softmax stats
        float mx = -3e38f;
        #pragma unroll
        for (int mt = 0; mt < 20; ++mt)
            #pragma unroll
            for (int i = 0; i < 4; ++i) mx = fmaxf(mx, s[mt][i]);
        mx = fmaxf(mx, __shfl_xor(mx, 16));
        mx = fmaxf(mx, __shfl_xor(mx, 32));

        // exp -> bf16 P over the dead ctx slice (wave-lockstep, no barrier)
        float sum = 0.f;
        #pragma unroll
        for (int mt = 0; mt < 20; ++mt) {
            bf16x4 p4;
            #pragma unroll
            for (int i = 0; i < 4; ++i) {
                const float e = __expf(s[mt][i] - mx);
                sum += e;
                p4[i] = (__bf16)e;
            }
            *(bf16x4*)&ctxls[wave][lr][mt * 16 + lg * 4] = p4;
        }
        sum += __shfl_xor(sum, 16);
        sum += __shfl_xor(sum, 32);
        const float rinv = 1.0f / sum;

        // O^T += VW^T x P^T from LDS
        f32x4 o0 = {0.f, 0.f, 0.f, 0.f}, o1 = {0.f, 0.f, 0.f, 0.f};
        #pragma unroll
        for (int ks = 0; ks < 10; ++ks) {
            const bf16x8 pfrag = *(const bf16x8*)&ctxls[wave][lr][ks * 32 + lg * 8];
            const bf16x8 vf0 = *(const bf16x8*)&vwls[lr][ks * 32 + lg * 8];
            const bf16x8 vf1 = *(const bf16x8*)&vwls[16 + lr][ks * 32 + lg * 8];
            o0 = __builtin_amdgcn_mfma_f32_16x16x32_bf16(vf0, pfrag, o0, 0, 0, 0);
            o1 = __builtin_amdgcn_mfma_f32_16x16x32_bf16(vf1, pfrag, o1, 0, 0, 0);
        }

        // per-head partial (normalized)
        float* pdst = ppan + (size_t)(nw + lr) * DH + lg * 4;
        f32x4 r0, r1;
        #pragma unroll
        for (int i = 0; i < 4; ++i) { r0[i] = o0[i] * rinv; r1[i] = o1[i] * rinv; }
        *(f32x4*)(pdst)      = r0;
        *(f32x4*)(pdst + 16) = r1;
    }
}

// ---------------- Kernel 5: 8-head reduce + output scatter ----------------
__global__ __launch_bounds__(256) void k_red(
    const float* __restrict__ part, float* __restrict__ out)
{
    const int idx = blockIdx.x * 256 + threadIdx.x;   // ROWS_T*8 total
    const int row = idx >> 3, q4 = (idx & 7) * 4;
    f32x4 a = {0.f, 0.f, 0.f, 0.f};
    #pragma unroll
    for (int h = 0; h < HEADS; ++h) {
        const f32x4 p = *(const f32x4*)(part + ((size_t)h * ROWS_T + row) * DH + q4);
        #pragma unroll
        for (int i = 0; i < 4; ++i) a[i] += p[i];
    }
    const int bb = row / NTOK, n = row % NTOK;
    const int b_idx = bb / 48, x_idx = (bb % 48) >> 3, y_idx = bb & 7;
    const int l_idx = n >> 6, w1_idx = (n >> 3) & 7, w2_idx = n & 7;
    const size_t dst =
        ((((((size_t)b_idx * 5 + l_idx) * 6 + x_idx) * 8 + y_idx) * 8 + w1_idx) * 8 + w2_idx) * (size_t)DH;
    *(f32x4*)(out + dst + q4) = a;
}

extern "C" void kernel_launch(void* const* d_in, const int* in_sizes, int n_in,
                              void* d_out, int out_size, void* d_ws, size_t ws_size,
                              hipStream_t stream) {
    const float* x    = (const float*)d_in[0];
    const float* ctx  = (const float*)d_in[1];
    const float* wq   = (const float*)d_in[2];
    const float* wkv  = (const float*)d_in[3];
    const float* wout = (const float*)d_in[4];
    const float* ln_g = (const float*)d_in[5];
    const float* ln_b = (const float*)d_in[6];
    float* out = (float*)d_out;

    // workspace: qhb|khb|vhb|yb bf16 (SEG each), wT bf16, vwt bf16 (SEG), part f32 (8*ROWS*32)
    const size_t SEG = (size_t)BWIN * NTOK * INNER;  // 7,864,320 elements
    __bf16* qhb = (__bf16*)d_ws;
    __bf16* khb = qhb + SEG;
    __bf16* vhb = khb + SEG;
    __bf16* yb  = vhb + SEG;
    __bf16* wT  = yb + SEG;
    __bf16* vwt = wT + 768 * 256;
    float*  part = (float*)(vwt + SEG);

    const int ROWS = BWIN * NTOK;  // 30720
    k_pre<<<768 + ROWS / 4, 256, 0, stream>>>(wq, wkv, x, ln_g, ln_b, wT, yb);
    k_qkv<<<dim3(ROWS / 128, 6), 256, 0, stream>>>(yb, wT, qhb, khb, vhb);
    k_vw<<<dim3(BWIN, HEADS), 256, 0, stream>>>(vhb, wout, vwt);
    k_attn<<<BWIN * HEADS, 128, 0, stream>>>(qhb, khb, vwt, ctx, part);
    k_red<<<ROWS * 8 / 256, 256, 0, stream>>>(part, out);
}

// Round 11
// 154.554 us; speedup vs baseline: 1.2783x; 1.0534x over previous
//
#include <hip/hip_runtime.h>
#include <hip/hip_bf16.h>

// Problem constants
#define BWIN 96      // b*gx*gy = 2*6*8
#define NTOK 320     // l*w1*w2 = 5*8*8
#define DIMX 256
#define HEADS 8
#define DH 32
#define INNER 256
#define CTXW 2560    // HEADS*NTOK
#define MPAD 328     // padded m-stride (bf16) for P/ctx/VW LDS rows
#define ROWS_T 30720 // BWIN*NTOK

typedef __bf16 bf16x8 __attribute__((ext_vector_type(8)));
typedef __bf16 bf16x4 __attribute__((ext_vector_type(4)));
typedef float f32x4 __attribute__((ext_vector_type(4)));

// ---------------- Kernel 1: fused weight-cast + LayerNorm ----------------
__global__ __launch_bounds__(256) void k_pre(
    const float* __restrict__ wq, const float* __restrict__ wkv,
    const float* __restrict__ x, const float* __restrict__ g,
    const float* __restrict__ bt, __bf16* __restrict__ wT,
    __bf16* __restrict__ y)
{
    const int t = threadIdx.x;
    if (blockIdx.x < 768) {
        const int col = blockIdx.x;
        float v;
        if (col < 256)      v = wq[t * 256 + col];
        else if (col < 512) v = wkv[t * 512 + (col - 256)];
        else                v = wkv[t * 512 + 256 + (col - 512)];
        wT[(size_t)col * 256 + t] = (__bf16)v;
        return;
    }
    const int wave = t >> 6, lane = t & 63;
    const int row = (blockIdx.x - 768) * 4 + wave;
    const int bb = row / NTOK, n = row % NTOK;
    const int b_idx = bb / 48, x_idx = (bb % 48) >> 3, y_idx = bb & 7;
    const int l_idx = n >> 6, w1_idx = (n >> 3) & 7, w2_idx = n & 7;
    const size_t src =
        ((((((size_t)b_idx * 5 + l_idx) * 6 + x_idx) * 8 + y_idx) * 8 + w1_idx) * 8 + w2_idx) * (size_t)DIMX;

    const float4 xv = *(const float4*)(x + src + lane * 4);
    float s = xv.x + xv.y + xv.z + xv.w;
    float ss = xv.x * xv.x + xv.y * xv.y + xv.z * xv.z + xv.w * xv.w;
    #pragma unroll
    for (int o = 32; o > 0; o >>= 1) {
        s += __shfl_xor(s, o);
        ss += __shfl_xor(ss, o);
    }
    const float mu = s * (1.0f / DIMX);
    const float var = ss * (1.0f / DIMX) - mu * mu;
    const float rsig = rsqrtf(var + 1e-5f);
    const float4 g4 = *(const float4*)(g + lane * 4);
    const float4 b4 = *(const float4*)(bt + lane * 4);
    bf16x4 yo;
    yo[0] = (__bf16)((xv.x - mu) * rsig * g4.x + b4.x);
    yo[1] = (__bf16)((xv.y - mu) * rsig * g4.y + b4.y);
    yo[2] = (__bf16)((xv.z - mu) * rsig * g4.z + b4.z);
    yo[3] = (__bf16)((xv.w - mu) * rsig * g4.w + b4.w);
    *(bf16x4*)(y + (size_t)row * DIMX + lane * 4) = yo;
}

// ---------------- Kernel 2: QKV GEMM -> head-major outputs ----------------
__global__ __launch_bounds__(256) void k_qkv(
    const __bf16* __restrict__ y, const __bf16* __restrict__ wT,
    __bf16* __restrict__ qhb, __bf16* __restrict__ khb, __bf16* __restrict__ vhb)
{
    __shared__ __bf16 yls[128][40];
    __shared__ __bf16 wls[128][40];
    const int t = threadIdx.x, wave = t >> 6, lane = t & 63;
    const int lr = lane & 15, lg = lane >> 4;
    const int wm = wave & 1, wn = wave >> 1;
    const int rbase = blockIdx.x * 128;
    const int cbase = blockIdx.y * 128;

    f32x4 acc[4][4];
    #pragma unroll
    for (int im = 0; im < 4; ++im)
        #pragma unroll
        for (int jn = 0; jn < 4; ++jn) acc[im][jn] = (f32x4){0.f, 0.f, 0.f, 0.f};

    const int srow = t >> 1, sseg = (t & 1) * 16;
    #pragma unroll
    for (int ks = 0; ks < 8; ++ks) {
        __syncthreads();
        #pragma unroll
        for (int j = 0; j < 2; ++j) {
            *(bf16x8*)&yls[srow][sseg + j * 8] =
                *(const bf16x8*)(y + (size_t)(rbase + srow) * DIMX + ks * 32 + sseg + j * 8);
            *(bf16x8*)&wls[srow][sseg + j * 8] =
                *(const bf16x8*)(wT + (size_t)(cbase + srow) * DIMX + ks * 32 + sseg + j * 8);
        }
        __syncthreads();

        bf16x8 yfr[4], wfr[4];
        #pragma unroll
        for (int jn = 0; jn < 4; ++jn) yfr[jn] = *(const bf16x8*)&yls[wm * 64 + jn * 16 + lr][lg * 8];
        #pragma unroll
        for (int im = 0; im < 4; ++im) wfr[im] = *(const bf16x8*)&wls[wn * 64 + im * 16 + lr][lg * 8];
        #pragma unroll
        for (int im = 0; im < 4; ++im)
            #pragma unroll
            for (int jn = 0; jn < 4; ++jn)
                acc[im][jn] = __builtin_amdgcn_mfma_f32_16x16x32_bf16(wfr[im], yfr[jn], acc[im][jn], 0, 0, 0);
    }

    #pragma unroll
    for (int im = 0; im < 4; ++im) {
        const int g = cbase + wn * 64 + im * 16 + lg * 4;   // global col 0..767
        const int which = g >> 8;
        __bf16* buf = (which == 0) ? qhb : (which == 1) ? khb : vhb;
        const int hh = (g & 255) >> 5, d = g & 31;
        #pragma unroll
        for (int jn = 0; jn < 4; ++jn) {
            const int row = rbase + wm * 64 + jn * 16 + lr;
            const int bb2 = row / NTOK, n2 = row % NTOK;
            bf16x4 p;
            #pragma unroll
            for (int i = 0; i < 4; ++i) p[i] = (__bf16)acc[im][jn][i];
            *(bf16x4*)(buf + ((size_t)(bb2 * 8 + hh) * NTOK + n2) * DH + d) = p;
        }
    }
}

// ---------------- Kernel 3: fused VW + K/VW-stationary attention ----------------
// grid (768) = (bb, h), h fastest; 128 thr = 2 waves.
// Block start: compute VW^T = wout_h^T @ V_h^T straight into LDS (40 MFMAs).
// K fragments read from the L1-resident head-major global panel (20 KB).
// Each wave loops 10 q-tiles: reg-prefetched ctx pipeline, P aliases dead ctx.
__global__ __launch_bounds__(128) void k_attn(
    const __bf16* __restrict__ qhb, const __bf16* __restrict__ khb,
    const __bf16* __restrict__ vhb, const float* __restrict__ wout,
    const float* __restrict__ ctx, float* __restrict__ part)
{
    __shared__ __bf16 vwls[DH][MPAD];       // 20,992 B
    __shared__ __bf16 ctxls[2][16][MPAD];   // 20,992 B (per-wave; P aliases)
    const int t = threadIdx.x, wave = t >> 6, lane = t & 63;
    const int lr = lane & 15, lg = lane >> 4;
    const int h = blockIdx.x & 7, bb = blockIdx.x >> 3;
    const size_t panel = (size_t)(bb * 8 + h);

    // --- compute VW^T into LDS: wave covers m = wave*160 .. +159 ---
    {
        bf16x8 afr[2];
        #pragma unroll
        for (int rt = 0; rt < 2; ++rt)
            #pragma unroll
            for (int j = 0; j < 8; ++j)
                afr[rt][j] = (__bf16)wout[(h * 32 + lg * 8 + j) * 32 + rt * 16 + lr];
        const __bf16* vbase = vhb + panel * NTOK * DH + lg * 8;
        #pragma unroll
        for (int mt = 0; mt < 10; ++mt) {
            const int m = wave * 160 + mt * 16 + lr;
            const bf16x8 bfr = *(const bf16x8*)(vbase + (size_t)m * DH);
            #pragma unroll
            for (int rt = 0; rt < 2; ++rt) {
                const f32x4 d4 = __builtin_amdgcn_mfma_f32_16x16x32_bf16(
                    afr[rt], bfr, (f32x4){0.f, 0.f, 0.f, 0.f}, 0, 0, 0);
                #pragma unroll
                for (int i = 0; i < 4; ++i)
                    vwls[rt * 16 + lg * 4 + i][wave * 160 + mt * 16 + lr] = (__bf16)d4[i];
            }
        }
    }
    __syncthreads();

    const float* cpan = ctx + (size_t)bb * NTOK * CTXW + h * NTOK;
    const __bf16* qpan = qhb + panel * NTOK * DH;
    const __bf16* kpan = khb + panel * NTOK * DH;
    float* ppan = part + ((size_t)h * ROWS_T + (size_t)bb * NTOK) * DH;

    // prologue: prefetch ctx tile for iteration 0 (wave's q-tile = 2*it + wave)
    float4 creg[20];
    {
        const float* cb = cpan + (size_t)(wave * 16) * CTXW;
        #pragma unroll
        for (int j = 0; j < 20; ++j) {
            const int f = j * 64 + lane, r = f / 80, c = f % 80;
            creg[j] = *(const float4*)(cb + (size_t)r * CTXW + c * 4);
        }
    }

    for (int it = 0; it < 10; ++it) {
        const int nw = (it * 2 + wave) * 16;

        // write current ctx regs -> LDS (bf16)
        #pragma unroll
        for (int j = 0; j < 20; ++j) {
            const int f = j * 64 + lane, r = f / 80, c = f % 80;
            bf16x4 b;
            b[0] = (__bf16)creg[j].x; b[1] = (__bf16)creg[j].y;
            b[2] = (__bf16)creg[j].z; b[3] = (__bf16)creg[j].w;
            *(bf16x4*)&ctxls[wave][r][c * 4] = b;
        }
        // prefetch next tile (overlaps the whole iteration below)
        if (it < 9) {
            const float* cb = cpan + (size_t)((it * 2 + 2 + wave) * 16) * CTXW;
            #pragma unroll
            for (int j = 0; j < 20; ++j) {
                const int f = j * 64 + lane, r = f / 80, c = f % 80;
                creg[j] = *(const float4*)(cb + (size_t)r * CTXW + c * 4);
            }
        }

        // Q fragment (head-major)
        const bf16x8 qfrag = *(const bf16x8*)(qpan + (size_t)(nw + lr) * DH + lg * 8);

        // S^T = mfma(K, Q); K fragments from L1-resident global panel
        f32x4 s[20];
        #pragma unroll
        for (int mt = 0; mt < 20; ++mt) {
            const bf16x8 kfrag = *(const bf16x8*)(kpan + (size_t)(mt * 16 + lr) * DH + lg * 8);
            s[mt] = __builtin_amdgcn_mfma_f32_16x16x32_bf16(kfrag, qfrag,
                                                            (f32x4){0.f, 0.f, 0.f, 0.f}, 0, 0, 0);
        }

        // bias add from this wave's ctx slice
        #pragma unroll
        for (int mt = 0; mt < 20; ++mt) {
            const bf16x4 c4 = *(const bf16x4*)&ctxls[wave][lr][mt * 16 + lg * 4];
            #pragma unroll
            for (int i = 0; i < 4; ++i) s[mt][i] += (float)c4[i];
        }

        // softmax stats
        float mx = -3e38f;
        #pragma unroll
        for (int mt = 0; mt < 20; ++mt)
            #pragma unroll
            for (int i = 0; i < 4; ++i) mx = fmaxf(mx, s[mt][i]);
        mx = fmaxf(mx, __shfl_xor(mx, 16));
        mx = fmaxf(mx, __shfl_xor(mx, 32));

        // exp -> bf16 P over the dead ctx slice (wave-lockstep, no barrier)
        float sum = 0.f;
        #pragma unroll
        for (int mt = 0; mt < 20; ++mt) {
            bf16x4 p4;
            #pragma unroll
            for (int i = 0; i < 4; ++i) {
                const float e = __expf(s[mt][i] - mx);
                sum += e;
                p4[i] = (__bf16)e;
            }
            *(bf16x4*)&ctxls[wave][lr][mt * 16 + lg * 4] = p4;
        }
        sum += __shfl_xor(sum, 16);
        sum += __shfl_xor(sum, 32);
        const float rinv = 1.0f / sum;

        // O^T += VW^T x P^T from LDS
        f32x4 o0 = {0.f, 0.f, 0.f, 0.f}, o1 = {0.f, 0.f, 0.f, 0.f};
        #pragma unroll
        for (int ks = 0; ks < 10; ++ks) {
            const bf16x8 pfrag = *(const bf16x8*)&ctxls[wave][lr][ks * 32 + lg * 8];
            const bf16x8 vf0 = *(const bf16x8*)&vwls[lr][ks * 32 + lg * 8];
            const bf16x8 vf1 = *(const bf16x8*)&vwls[16 + lr][ks * 32 + lg * 8];
            o0 = __builtin_amdgcn_mfma_f32_16x16x32_bf16(vf0, pfrag, o0, 0, 0, 0);
            o1 = __builtin_amdgcn_mfma_f32_16x16x32_bf16(vf1, pfrag, o1, 0, 0, 0);
        }

        // per-head partial (normalized)
        float* pdst = ppan + (size_t)(nw + lr) * DH + lg * 4;
        f32x4 r0, r1;
        #pragma unroll
        for (int i = 0; i < 4; ++i) { r0[i] = o0[i] * rinv; r1[i] = o1[i] * rinv; }
        *(f32x4*)(pdst)      = r0;
        *(f32x4*)(pdst + 16) = r1;
    }
}

// ---------------- Kernel 4: 8-head reduce + output scatter ----------------
__global__ __launch_bounds__(256) void k_red(
    const float* __restrict__ part, float* __restrict__ out)
{
    const int idx = blockIdx.x * 256 + threadIdx.x;   // ROWS_T*8 total
    const int row = idx >> 3, q4 = (idx & 7) * 4;
    f32x4 a = {0.f, 0.f, 0.f, 0.f};
    #pragma unroll
    for (int h = 0; h < HEADS; ++h) {
        const f32x4 p = *(const f32x4*)(part + ((size_t)h * ROWS_T + row) * DH + q4);
        #pragma unroll
        for (int i = 0; i < 4; ++i) a[i] += p[i];
    }
    const int bb = row / NTOK, n = row % NTOK;
    const int b_idx = bb / 48, x_idx = (bb % 48) >> 3, y_idx = bb & 7;
    const int l_idx = n >> 6, w1_idx = (n >> 3) & 7, w2_idx = n & 7;
    const size_t dst =
        ((((((size_t)b_idx * 5 + l_idx) * 6 + x_idx) * 8 + y_idx) * 8 + w1_idx) * 8 + w2_idx) * (size_t)DH;
    *(f32x4*)(out + dst + q4) = a;
}

extern "C" void kernel_launch(void* const* d_in, const int* in_sizes, int n_in,
                              void* d_out, int out_size, void* d_ws, size_t ws_size,
                              hipStream_t stream) {
    const float* x    = (const float*)d_in[0];
    const float* ctx  = (const float*)d_in[1];
    const float* wq   = (const float*)d_in[2];
    const float* wkv  = (const float*)d_in[3];
    const float* wout = (const float*)d_in[4];
    const float* ln_g = (const float*)d_in[5];
    const float* ln_b = (const float*)d_in[6];
    float* out = (float*)d_out;

    // workspace: qhb|khb|vhb|yb bf16 (SEG each), wT bf16, part f32 (8*ROWS*32)
    const size_t SEG = (size_t)BWIN * NTOK * INNER;  // 7,864,320 elements
    __bf16* qhb = (__bf16*)d_ws;
    __bf16* khb = qhb + SEG;
    __bf16* vhb = khb + SEG;
    __bf16* yb  = vhb + SEG;
    __bf16* wT  = yb + SEG;
    float*  part = (float*)(wT + 768 * 256);

    const int ROWS = BWIN * NTOK;  // 30720
    k_pre<<<768 + ROWS / 4, 256, 0, stream>>>(wq, wkv, x, ln_g, ln_b, wT, yb);
    k_qkv<<<dim3(ROWS / 128, 6), 256, 0, stream>>>(yb, wT, qhb, khb, vhb);
    k_attn<<<BWIN * HEADS, 128, 0, stream>>>(qhb, khb, vhb, wout, ctx, part);
    k_red<<<ROWS * 8 / 256, 256, 0, stream>>>(part, out);
}